// Round 9
// baseline (105.540 us; speedup 1.0000x reference)
//
#include <hip/hip_runtime.h>
#include <stdint.h>

#define B_ 2
#define C_ 512
#define G_ 2048
#define H_ 32
#define D_ 128
#define F_ 64
#define N_ (G_ + C_)      // 2560
#define NPAD 4096

// padded LDS slot for the sort's cross-wave exchanges
#define PIDX(i) ((i) + ((i) >> 4))

// native vector type for __builtin_nontemporal_* (HIP float4 is a class and
// is rejected by the builtin; this alias is layout-identical)
typedef float nt_f4 __attribute__((ext_vector_type(4)));

__device__ __forceinline__ unsigned long long shfl64_xor(unsigned long long x,
                                                         int lanex) {
  unsigned int lo = (unsigned int)x, hi = (unsigned int)(x >> 32);
  lo = __shfl_xor(lo, lanex, 64);
  hi = __shfl_xor(hi, lanex, 64);
  return ((unsigned long long)hi << 32) | (unsigned long long)lo;
}

// ---------------------------------------------------------------------------
// Kernel 1: per-(b,h) stable descending argsort of 2560 scores.
// Bitonic sort of 4096 uint64 keys, 512 threads x 8 register-resident elems.
// key = (~orderable(score) << 32) | index  (unique keys -> exact stable sort).
// Emits: heap_new (bit-exact scores), ws_idx (rank -> src index, for accum),
//        ws_inv (src index -> rank, for the scatter copy).
// Verified bit-exact (rounds 4/7/8: absmax 0.0).
// ---------------------------------------------------------------------------
__global__ __launch_bounds__(512) void sort_kernel(
    const float* __restrict__ heap_score,   // (B,G,H)
    const float* __restrict__ score_c,      // (B,C,H)
    float* __restrict__ heap_new,           // (B,G,H)
    int* __restrict__ ws_idx,               // (B*H, 2560) rank -> src
    int* __restrict__ ws_inv)               // (B*H, 2560) src -> rank
{
  __shared__ unsigned long long keys[NPAD + (NPAD >> 4)];   // 34 KB
  const int blk = blockIdx.x;               // b*H + h
  const int b = blk >> 5, h = blk & 31;
  const int tid = threadIdx.x;

  unsigned long long v[8];
  #pragma unroll
  for (int l = 0; l < 8; ++l) {
    int r = tid * 8 + l;
    unsigned long long key = 0xFFFFFFFFFFFFFFFFull;   // dummy sinks to end
    if (r < N_) {
      float s = (r < G_) ? heap_score[((size_t)b * G_ + r) * H_ + h]
                         : score_c[((size_t)b * C_ + (r - G_)) * H_ + h];
      unsigned int bits = __float_as_uint(s);
      unsigned int ord = (bits & 0x80000000u) ? ~bits : (bits | 0x80000000u);
      key = ((unsigned long long)(~ord) << 32) | (unsigned int)r;
    }
    v[l] = key;
  }

  auto ce = [&](int x, int y, bool desc) {
    unsigned long long a = v[x], c = v[y];
    if ((a > c) != desc) { v[x] = c; v[y] = a; }
  };

  // ---- build sorted runs of 8 (stages k=2,4,8; i = 8*tid + l) ------------
  {
    const bool t1 = (tid & 1) != 0;         // (i & 8)
    ce(0,1,false); ce(2,3,true);  ce(4,5,false); ce(6,7,true);   // k=2
    ce(0,2,false); ce(1,3,false); ce(4,6,true);  ce(5,7,true);   // k=4 j=2
    ce(0,1,false); ce(2,3,false); ce(4,5,true);  ce(6,7,true);   // k=4 j=1
    ce(0,4,t1); ce(1,5,t1); ce(2,6,t1); ce(3,7,t1);              // k=8 j=4
    ce(0,2,t1); ce(1,3,t1); ce(4,6,t1); ce(5,7,t1);              // k=8 j=2
    ce(0,1,t1); ce(2,3,t1); ce(4,5,t1); ce(6,7,t1);              // k=8 j=1
  }

  // ---- stages k=16..4096 --------------------------------------------------
  for (int k = 16; k <= NPAD; k <<= 1) {
    const bool desc = (((unsigned)tid << 3) & (unsigned)k) != 0;  // (8t & k)

    for (int j = k >> 1; j >= 512; j >>= 1) {         // cross-wave: LDS
      __syncthreads();                                 // protect prior reads
      #pragma unroll
      for (int l = 0; l < 8; ++l) keys[PIDX(tid * 8 + l)] = v[l];
      __syncthreads();
      const int pt = tid ^ (j >> 3);
      const bool up = (tid & (j >> 3)) != 0;
      #pragma unroll
      for (int l = 0; l < 8; ++l) {
        unsigned long long o = keys[PIDX(pt * 8 + l)];
        unsigned long long mn = (v[l] < o) ? v[l] : o;
        unsigned long long mx = (v[l] < o) ? o : v[l];
        v[l] = (up != desc) ? mx : mn;
      }
    }

    #pragma unroll
    for (int j = 256; j >= 8; j >>= 1) {              // in-wave: shuffles
      if (j <= (k >> 1)) {
        const int lanex = j >> 3;                     // 1..32
        const bool up = (tid & lanex) != 0;
        #pragma unroll
        for (int l = 0; l < 8; ++l) {
          unsigned long long o = shfl64_xor(v[l], lanex);
          unsigned long long mn = (v[l] < o) ? v[l] : o;
          unsigned long long mx = (v[l] < o) ? o : v[l];
          v[l] = (up != desc) ? mx : mn;
        }
      }
    }

    ce(0,4,desc); ce(1,5,desc); ce(2,6,desc); ce(3,7,desc);      // j=4
    ce(0,2,desc); ce(1,3,desc); ce(4,6,desc); ce(5,7,desc);      // j=2
    ce(0,1,desc); ce(2,3,desc); ce(4,5,desc); ce(6,7,desc);      // j=1
  }

  // ---- outputs straight from registers -----------------------------------
  if (tid < N_ / 8) {                                  // tid < 320
    int4 lo4 = { (int)(unsigned)v[0], (int)(unsigned)v[1],
                 (int)(unsigned)v[2], (int)(unsigned)v[3] };
    int4 hi4 = { (int)(unsigned)v[4], (int)(unsigned)v[5],
                 (int)(unsigned)v[6], (int)(unsigned)v[7] };
    int4* p = (int4*)(ws_idx + (size_t)blk * N_);
    p[2 * tid] = lo4;
    p[2 * tid + 1] = hi4;
    #pragma unroll
    for (int l = 0; l < 8; ++l) {                      // inverse permutation
      int r = tid * 8 + l;
      ws_inv[(size_t)blk * N_ + (unsigned)v[l]] = r;
    }
  }
  if (tid < G_ / 8) {                                  // tid < 256
    #pragma unroll
    for (int l = 0; l < 8; ++l) {
      int r = tid * 8 + l;
      unsigned int ord = ~(unsigned int)(v[l] >> 32);
      unsigned int bits = (ord & 0x80000000u) ? (ord & 0x7FFFFFFFu) : ~ord;
      heap_new[((size_t)b * G_ + r) * H_ + h] = __uint_as_float(bits);
    }
  }
}

// ---------------------------------------------------------------------------
// Kernel 2: fused scatter-copy + accumulation.
//  blocks [0, ABLOCKS): accum — 2 blocks per (b,h) (one per d-half), direct
//    H_new = H_sum + sum over 512 bottom rows (bit-exact vs np, round 7).
//  blocks [ABLOCKS, +NS): scatter — LINEAR reads over the six source arrays
//    (coalesced full-BW streaming, NT to keep L2 for inv), rank looked up in
//    ws_inv (independent of the data load -> both issue in parallel, ILP-8),
//    predicated scattered store to the rank-th output row (posted writes).
// ---------------------------------------------------------------------------
#define KT4 ((long long)B_ * G_ * H_ * (D_ / 4))       // 4194304
#define KC4 ((long long)B_ * C_ * H_ * (D_ / 4))       // 1048576
#define FT4 ((long long)B_ * G_ * H_ * (F_ / 4))       // 2097152
#define FC4 ((long long)B_ * C_ * H_ * (F_ / 4))       // 524288
#define E0 (KT4)                                       // 4194304
#define E1 (E0 + KC4)                                  // 5242880
#define E2 (E1 + KT4)                                  // 9437184
#define E3 (E2 + KC4)                                  // 10485760
#define E4 (E3 + FT4)                                  // 12582912
#define ETOT (E4 + FC4)                                // 13107200
#define EIGHTH_S (ETOT / 8)                            // 1638400 (mult of 256)
#define NS ((int)(EIGHTH_S / 256))                     // 6400 scatter blocks
#define ABLOCKS (2 * B_ * H_)                          // 128 accum blocks
#define ACHUNK 16
#define AITER (C_ / ACHUNK)                            // 32

__device__ __forceinline__ void scatter_one(
    long long gid,
    const float4* __restrict__ K_top,  const float4* __restrict__ k_c,
    const float4* __restrict__ V_top,  const float4* __restrict__ v_c,
    const float4* __restrict__ FK_top, const float4* __restrict__ fk_c,
    float4* __restrict__ K_new, float4* __restrict__ V_new,
    float4* __restrict__ FK_new,
    const int* __restrict__ ws_inv,
    const nt_f4** src, float4** dst, int* rank_out)
{
  const float4* sbase;
  float4* dbase;
  int lg;
  long long g2;
  bool is_c;
  if (gid < E0)      { sbase = K_top;  dbase = K_new;  lg = 5; g2 = gid;      is_c = false; }
  else if (gid < E1) { sbase = k_c;    dbase = K_new;  lg = 5; g2 = gid - E0; is_c = true; }
  else if (gid < E2) { sbase = V_top;  dbase = V_new;  lg = 5; g2 = gid - E1; is_c = false; }
  else if (gid < E3) { sbase = v_c;    dbase = V_new;  lg = 5; g2 = gid - E2; is_c = true; }
  else if (gid < E4) { sbase = FK_top; dbase = FK_new; lg = 4; g2 = gid - E3; is_c = false; }
  else               { sbase = fk_c;   dbase = FK_new; lg = 4; g2 = gid - E4; is_c = true; }

  int row = (int)(g2 >> lg);
  int lane = (int)(g2 & ((1 << lg) - 1));
  int h = row & 31;
  int b, sidx;
  if (is_c) { b = row >> 14; sidx = G_ + ((row >> 5) & (C_ - 1)); }  // C*H rows/b
  else      { b = row >> 16; sidx = (row >> 5) & (G_ - 1); }          // G*H rows/b

  int rank = ws_inv[(size_t)((b << 5) | h) * N_ + sidx];
  *src = (const nt_f4*)(sbase + g2);
  *dst = dbase + (((size_t)(b * G_ + rank) * H_ + h) << lg) + lane;
  *rank_out = rank;
}

__global__ __launch_bounds__(256) void fused_kernel(
    const float4* __restrict__ K_top,  const float4* __restrict__ k_c,
    const float4* __restrict__ V_top,  const float4* __restrict__ v_c,
    const float4* __restrict__ FK_top, const float4* __restrict__ fk_c,
    float4* __restrict__ K_new, float4* __restrict__ V_new,
    float4* __restrict__ FK_new,
    const float* __restrict__ H_sum, const float* __restrict__ S_sum,
    float* __restrict__ H_new, float* __restrict__ S_new,
    const int* __restrict__ ws_idx, const int* __restrict__ ws_inv)
{
  __shared__ float fk_s[ACHUNK][F_];        // 4 KB
  __shared__ float v_s[ACHUNK][D_ / 2];     // 4 KB
  __shared__ int idx_all[C_];               // 2 KB

  const int tid = threadIdx.x;

  if (blockIdx.x >= ABLOCKS) {
    // ----- scatter: linear NT reads, rank-scattered predicated stores ----
    long long gid = (long long)(blockIdx.x - ABLOCKS) * 256 + tid;

    const nt_f4* s[8];
    float4* d[8];
    int rk[8];
    #pragma unroll
    for (int k = 0; k < 8; ++k)
      scatter_one(gid + (long long)k * EIGHTH_S, K_top, k_c, V_top, v_c,
                  FK_top, fk_c, K_new, V_new, FK_new, ws_inv,
                  &s[k], &d[k], &rk[k]);
    nt_f4 val[8];
    #pragma unroll
    for (int k = 0; k < 8; ++k) val[k] = __builtin_nontemporal_load(s[k]);
    #pragma unroll
    for (int k = 0; k < 8; ++k)
      if (rk[k] < G_) *(nt_f4*)d[k] = val[k];
    return;
  }

  // ----- accum: one block per (b,h) x d-half ----------------------------
  const int pair = blockIdx.x >> 1;         // 0..63
  const int dhalf = blockIdx.x & 1;
  const int b = pair >> 5, h = pair & 31;

  for (int i = tid; i < C_; i += 256)
    idx_all[i] = ws_idx[(size_t)pair * N_ + G_ + i];

  const int f0 = (tid >> 4) * 4;            // 0..60 (global f)
  const int d0 = (tid & 15) * 4;            // 0..60 (within half)
  float acc[4][4];
  #pragma unroll
  for (int i = 0; i < 4; i++)
    #pragma unroll
    for (int j = 0; j < 4; j++) acc[i][j] = 0.f;
  float sacc = 0.f;

  const int rr = tid >> 4, lane = tid & 15; // staging role: row, f4-slot

  for (int it = 0; it < AITER; ++it) {
    __syncthreads();                        // idx ready / prev compute done
    int idx = idx_all[it * ACHUNK + rr];
    {                                       // V half: 256 f4, 1 per thread
      const float4* src = (idx < G_)
          ? V_top + (((size_t)(b * G_ + idx) * H_ + h) << 5)
          : v_c  + (((size_t)(b * C_ + (idx - G_)) * H_ + h) << 5);
      ((float4*)v_s)[tid] = src[dhalf * 16 + lane];
    }
    {                                       // FK: 256 f4, 1 per thread
      const float4* src = (idx < G_)
          ? FK_top + (((size_t)(b * G_ + idx) * H_ + h) << 4)
          : fk_c  + (((size_t)(b * C_ + (idx - G_)) * H_ + h) << 4);
      ((float4*)fk_s)[tid] = src[lane];
    }
    __syncthreads();

    #pragma unroll 4
    for (int cc = 0; cc < ACHUNK; ++cc) {
      float4 fk4 = *(const float4*)&fk_s[cc][f0];
      float4 vv = *(const float4*)&v_s[cc][d0];
      float fs[4] = {fk4.x, fk4.y, fk4.z, fk4.w};
      float vs[4] = {vv.x, vv.y, vv.z, vv.w};
      #pragma unroll
      for (int i = 0; i < 4; i++)
        #pragma unroll
        for (int j = 0; j < 4; j++)
          acc[i][j] = fmaf(fs[i], vs[j], acc[i][j]);
    }
    if (dhalf == 0 && tid < F_) {
      float s = 0.f;
      #pragma unroll
      for (int cc = 0; cc < ACHUNK; ++cc) s += fk_s[cc][tid];
      sacc += s;
    }
  }

  // ----- epilogue: H_new = H_sum + acc, S_new = S_sum + sacc ------------
  const float* Hs = H_sum + (size_t)pair * F_ * D_;
  float* Hn = H_new + (size_t)pair * F_ * D_;
  #pragma unroll
  for (int i = 0; i < 4; i++) {
    size_t off = (size_t)(f0 + i) * D_ + dhalf * (D_ / 2) + d0;
    float4 hv = *(const float4*)&Hs[off];
    hv.x += acc[i][0]; hv.y += acc[i][1]; hv.z += acc[i][2]; hv.w += acc[i][3];
    *(float4*)&Hn[off] = hv;
  }
  if (dhalf == 0 && tid < F_)
    S_new[(size_t)pair * F_ + tid] = S_sum[(size_t)pair * F_ + tid] + sacc;
}

extern "C" void kernel_launch(void* const* d_in, const int* in_sizes, int n_in,
                              void* d_out, int out_size, void* d_ws, size_t ws_size,
                              hipStream_t stream) {
  const float* heap_score = (const float*)d_in[0];
  const float* K_top  = (const float*)d_in[1];
  const float* V_top  = (const float*)d_in[2];
  const float* FK_top = (const float*)d_in[3];
  const float* H_sum  = (const float*)d_in[4];
  const float* S_sum  = (const float*)d_in[5];
  const float* k_c    = (const float*)d_in[6];
  const float* v_c    = (const float*)d_in[7];
  const float* fk_c   = (const float*)d_in[8];
  const float* score_c = (const float*)d_in[9];

  float* out = (float*)d_out;
  float* heap_new = out;                                        // B*G*H
  float* K_new  = heap_new + (size_t)B_ * G_ * H_;              // B*G*H*D
  float* V_new  = K_new + (size_t)B_ * G_ * H_ * D_;
  float* FK_new = V_new + (size_t)B_ * G_ * H_ * D_;            // B*G*H*F
  float* H_new  = FK_new + (size_t)B_ * G_ * H_ * F_;           // B*H*F*D
  float* S_new  = H_new + (size_t)B_ * H_ * F_ * D_;            // B*H*F

  int* ws_idx = (int*)d_ws;                                     // 655360 B
  int* ws_inv = ws_idx + (size_t)B_ * H_ * N_;                  // 655360 B

  sort_kernel<<<B_ * H_, 512, 0, stream>>>(heap_score, score_c, heap_new,
                                           ws_idx, ws_inv);

  fused_kernel<<<ABLOCKS + NS, 256, 0, stream>>>(
      (const float4*)K_top, (const float4*)k_c,
      (const float4*)V_top, (const float4*)v_c,
      (const float4*)FK_top, (const float4*)fk_c,
      (float4*)K_new, (float4*)V_new, (float4*)FK_new,
      H_sum, S_sum, H_new, S_new, ws_idx, ws_inv);
}

// Round 10
// 102.911 us; speedup vs baseline: 1.0255x; 1.0255x over previous
//
#include <hip/hip_runtime.h>
#include <stdint.h>

#define B_ 2
#define C_ 512
#define G_ 2048
#define H_ 32
#define D_ 128
#define F_ 64
#define N_ (G_ + C_)      // 2560
#define NPAD 4096

// padded LDS slot for the sort's cross-wave exchanges
#define PIDX(i) ((i) + ((i) >> 4))

// native vector type for __builtin_nontemporal_* (HIP float4 is a class and
// is rejected by the builtin; this alias is layout-identical)
typedef float nt_f4 __attribute__((ext_vector_type(4)));

__device__ __forceinline__ unsigned long long shfl64_xor(unsigned long long x,
                                                         int lanex) {
  unsigned int lo = (unsigned int)x, hi = (unsigned int)(x >> 32);
  lo = __shfl_xor(lo, lanex, 64);
  hi = __shfl_xor(hi, lanex, 64);
  return ((unsigned long long)hi << 32) | (unsigned long long)lo;
}

// ---------------------------------------------------------------------------
// Kernel 1: per-(b,h) stable descending argsort of 2560 scores.
// Bitonic sort of 4096 uint64 keys, 512 threads x 8 register-resident elems.
// key = (~orderable(score) << 32) | index  (unique keys -> exact stable sort).
// Verified bit-exact (rounds 4/7/8/9: absmax 0.0).
// ---------------------------------------------------------------------------
__global__ __launch_bounds__(512) void sort_kernel(
    const float* __restrict__ heap_score,   // (B,G,H)
    const float* __restrict__ score_c,      // (B,C,H)
    float* __restrict__ heap_new,           // (B,G,H)
    int* __restrict__ ws_idx)               // (B*H, 2560)
{
  __shared__ unsigned long long keys[NPAD + (NPAD >> 4)];   // 34 KB
  const int blk = blockIdx.x;               // b*H + h
  const int b = blk >> 5, h = blk & 31;
  const int tid = threadIdx.x;

  unsigned long long v[8];
  #pragma unroll
  for (int l = 0; l < 8; ++l) {
    int r = tid * 8 + l;
    unsigned long long key = 0xFFFFFFFFFFFFFFFFull;   // dummy sinks to end
    if (r < N_) {
      float s = (r < G_) ? heap_score[((size_t)b * G_ + r) * H_ + h]
                         : score_c[((size_t)b * C_ + (r - G_)) * H_ + h];
      unsigned int bits = __float_as_uint(s);
      unsigned int ord = (bits & 0x80000000u) ? ~bits : (bits | 0x80000000u);
      key = ((unsigned long long)(~ord) << 32) | (unsigned int)r;
    }
    v[l] = key;
  }

  auto ce = [&](int x, int y, bool desc) {
    unsigned long long a = v[x], c = v[y];
    if ((a > c) != desc) { v[x] = c; v[y] = a; }
  };

  // ---- build sorted runs of 8 (stages k=2,4,8; i = 8*tid + l) ------------
  {
    const bool t1 = (tid & 1) != 0;         // (i & 8)
    ce(0,1,false); ce(2,3,true);  ce(4,5,false); ce(6,7,true);   // k=2
    ce(0,2,false); ce(1,3,false); ce(4,6,true);  ce(5,7,true);   // k=4 j=2
    ce(0,1,false); ce(2,3,false); ce(4,5,true);  ce(6,7,true);   // k=4 j=1
    ce(0,4,t1); ce(1,5,t1); ce(2,6,t1); ce(3,7,t1);              // k=8 j=4
    ce(0,2,t1); ce(1,3,t1); ce(4,6,t1); ce(5,7,t1);              // k=8 j=2
    ce(0,1,t1); ce(2,3,t1); ce(4,5,t1); ce(6,7,t1);              // k=8 j=1
  }

  // ---- stages k=16..4096 --------------------------------------------------
  for (int k = 16; k <= NPAD; k <<= 1) {
    const bool desc = (((unsigned)tid << 3) & (unsigned)k) != 0;  // (8t & k)

    for (int j = k >> 1; j >= 512; j >>= 1) {         // cross-wave: LDS
      __syncthreads();                                 // protect prior reads
      #pragma unroll
      for (int l = 0; l < 8; ++l) keys[PIDX(tid * 8 + l)] = v[l];
      __syncthreads();
      const int pt = tid ^ (j >> 3);
      const bool up = (tid & (j >> 3)) != 0;
      #pragma unroll
      for (int l = 0; l < 8; ++l) {
        unsigned long long o = keys[PIDX(pt * 8 + l)];
        unsigned long long mn = (v[l] < o) ? v[l] : o;
        unsigned long long mx = (v[l] < o) ? o : v[l];
        v[l] = (up != desc) ? mx : mn;
      }
    }

    #pragma unroll
    for (int j = 256; j >= 8; j >>= 1) {              // in-wave: shuffles
      if (j <= (k >> 1)) {
        const int lanex = j >> 3;                     // 1..32
        const bool up = (tid & lanex) != 0;
        #pragma unroll
        for (int l = 0; l < 8; ++l) {
          unsigned long long o = shfl64_xor(v[l], lanex);
          unsigned long long mn = (v[l] < o) ? v[l] : o;
          unsigned long long mx = (v[l] < o) ? o : v[l];
          v[l] = (up != desc) ? mx : mn;
        }
      }
    }

    ce(0,4,desc); ce(1,5,desc); ce(2,6,desc); ce(3,7,desc);      // j=4
    ce(0,2,desc); ce(1,3,desc); ce(4,6,desc); ce(5,7,desc);      // j=2
    ce(0,1,desc); ce(2,3,desc); ce(4,5,desc); ce(6,7,desc);      // j=1
  }

  // ---- outputs straight from registers -----------------------------------
  if (tid < N_ / 8) {                                  // tid < 320
    int4 lo4 = { (int)(unsigned)v[0], (int)(unsigned)v[1],
                 (int)(unsigned)v[2], (int)(unsigned)v[3] };
    int4 hi4 = { (int)(unsigned)v[4], (int)(unsigned)v[5],
                 (int)(unsigned)v[6], (int)(unsigned)v[7] };
    int4* p = (int4*)(ws_idx + (size_t)blk * N_);
    p[2 * tid] = lo4;
    p[2 * tid + 1] = hi4;
  }
  if (tid < G_ / 8) {                                  // tid < 256
    #pragma unroll
    for (int l = 0; l < 8; ++l) {
      int r = tid * 8 + l;
      unsigned int ord = ~(unsigned int)(v[l] >> 32);
      unsigned int bits = (ord & 0x80000000u) ? (ord & 0x7FFFFFFFu) : ~ord;
      heap_new[((size_t)b * G_ + r) * H_ + h] = __uint_as_float(bits);
    }
  }
}

// ---------------------------------------------------------------------------
// Kernel 2: fused gather + accumulation.
//  blocks [0, ABLOCKS): accum — 2 blocks per (b,h) (one per d-half), direct
//    H_new = H_sum + sum over 512 bottom rows (bit-exact vs np since R7).
//  blocks [ABLOCKS, +NG): gather — 16 chains per thread as a 2x8 software
//    pipeline: group A loads issued, group B loads issued, then stores A,
//    stores B. ~16 data loads in flight per thread. NT loads (read-once),
//    plain stores (L2 write path).
// ---------------------------------------------------------------------------
#define NK4 ((long long)B_ * G_ * H_ * (D_ / 4))       // 4194304
#define NTOT4 ((long long)B_ * G_ * H_ * (2 * (D_ / 4) + (F_ / 4)))  // 10485760
#define SIXT (NTOT4 / 16)                              // 655360 (mult of 256)
#define NG ((int)(SIXT / 256))                         // 2560 gather blocks
#define ABLOCKS (2 * B_ * H_)                          // 128 accum blocks
#define ACHUNK 16
#define AITER (C_ / ACHUNK)                            // 32

__device__ __forceinline__ void gather_one(
    long long gid,
    const float4* __restrict__ K_top,  const float4* __restrict__ k_c,
    const float4* __restrict__ V_top,  const float4* __restrict__ v_c,
    const float4* __restrict__ FK_top, const float4* __restrict__ fk_c,
    float4* __restrict__ K_new, float4* __restrict__ V_new,
    float4* __restrict__ FK_new,
    const int* __restrict__ ws_idx,
    const nt_f4** src, float4** dst)
{
  const float4 *top, *cc;
  float4* d;
  int lg;
  long long g2;
  if (gid < NK4)          { top = K_top;  cc = k_c;  d = K_new;  lg = 5; g2 = gid; }
  else if (gid < 2 * NK4) { top = V_top;  cc = v_c;  d = V_new;  lg = 5; g2 = gid - NK4; }
  else                    { top = FK_top; cc = fk_c; d = FK_new; lg = 4; g2 = gid - 2 * NK4; }

  int row = (int)(g2 >> lg);                // [0, B*G*H)
  int lane = (int)(g2 & ((1 << lg) - 1));
  int b = row >> 16;                        // G*H = 65536
  int g = (row >> 5) & (G_ - 1);
  int h = row & 31;
  int idx = ws_idx[((b << 5) | h) * N_ + g];
  const float4* s;
  if (idx < G_) s = top + (((size_t)(b * G_ + idx) * H_ + h) << lg) + lane;
  else          s = cc  + (((size_t)(b * C_ + (idx - G_)) * H_ + h) << lg) + lane;
  *src = (const nt_f4*)s;
  *dst = d + g2;
}

__global__ __launch_bounds__(256) void fused_kernel(
    const float4* __restrict__ K_top,  const float4* __restrict__ k_c,
    const float4* __restrict__ V_top,  const float4* __restrict__ v_c,
    const float4* __restrict__ FK_top, const float4* __restrict__ fk_c,
    float4* __restrict__ K_new, float4* __restrict__ V_new,
    float4* __restrict__ FK_new,
    const float* __restrict__ H_sum, const float* __restrict__ S_sum,
    float* __restrict__ H_new, float* __restrict__ S_new,
    const int* __restrict__ ws_idx)
{
  __shared__ float fk_s[ACHUNK][F_];        // 4 KB
  __shared__ float v_s[ACHUNK][D_ / 2];     // 4 KB
  __shared__ int idx_all[C_];               // 2 KB

  const int tid = threadIdx.x;

  if (blockIdx.x >= ABLOCKS) {
    // ----- gather: 2x8 pipelined chains, NT loads + plain stores --------
    long long gid = (long long)(blockIdx.x - ABLOCKS) * 256 + tid;

    const nt_f4* sA[8];
    float4* dA[8];
    nt_f4 valA[8];
    #pragma unroll
    for (int k = 0; k < 8; ++k)
      gather_one(gid + (long long)k * SIXT, K_top, k_c, V_top, v_c,
                 FK_top, fk_c, K_new, V_new, FK_new, ws_idx, &sA[k], &dA[k]);
    #pragma unroll
    for (int k = 0; k < 8; ++k) valA[k] = __builtin_nontemporal_load(sA[k]);

    const nt_f4* sB[8];
    float4* dB[8];
    nt_f4 valB[8];
    #pragma unroll
    for (int k = 0; k < 8; ++k)
      gather_one(gid + (long long)(k + 8) * SIXT, K_top, k_c, V_top, v_c,
                 FK_top, fk_c, K_new, V_new, FK_new, ws_idx, &sB[k], &dB[k]);
    #pragma unroll
    for (int k = 0; k < 8; ++k) valB[k] = __builtin_nontemporal_load(sB[k]);

    #pragma unroll
    for (int k = 0; k < 8; ++k) *(nt_f4*)dA[k] = valA[k];
    #pragma unroll
    for (int k = 0; k < 8; ++k) *(nt_f4*)dB[k] = valB[k];
    return;
  }

  // ----- accum: one block per (b,h) x d-half ----------------------------
  const int pair = blockIdx.x >> 1;         // 0..63
  const int dhalf = blockIdx.x & 1;
  const int b = pair >> 5, h = pair & 31;

  for (int i = tid; i < C_; i += 256)
    idx_all[i] = ws_idx[(size_t)pair * N_ + G_ + i];

  const int f0 = (tid >> 4) * 4;            // 0..60 (global f)
  const int d0 = (tid & 15) * 4;            // 0..60 (within half)
  float acc[4][4];
  #pragma unroll
  for (int i = 0; i < 4; i++)
    #pragma unroll
    for (int j = 0; j < 4; j++) acc[i][j] = 0.f;
  float sacc = 0.f;

  const int rr = tid >> 4, lane = tid & 15; // staging role: row, f4-slot

  for (int it = 0; it < AITER; ++it) {
    __syncthreads();                        // idx ready / prev compute done
    int idx = idx_all[it * ACHUNK + rr];
    {                                       // V half: 256 f4, 1 per thread
      const float4* src = (idx < G_)
          ? V_top + (((size_t)(b * G_ + idx) * H_ + h) << 5)
          : v_c  + (((size_t)(b * C_ + (idx - G_)) * H_ + h) << 5);
      ((float4*)v_s)[tid] = src[dhalf * 16 + lane];
    }
    {                                       // FK: 256 f4, 1 per thread
      const float4* src = (idx < G_)
          ? FK_top + (((size_t)(b * G_ + idx) * H_ + h) << 4)
          : fk_c  + (((size_t)(b * C_ + (idx - G_)) * H_ + h) << 4);
      ((float4*)fk_s)[tid] = src[lane];
    }
    __syncthreads();

    #pragma unroll 4
    for (int cc = 0; cc < ACHUNK; ++cc) {
      float4 fk4 = *(const float4*)&fk_s[cc][f0];
      float4 vv = *(const float4*)&v_s[cc][d0];
      float fs[4] = {fk4.x, fk4.y, fk4.z, fk4.w};
      float vs[4] = {vv.x, vv.y, vv.z, vv.w};
      #pragma unroll
      for (int i = 0; i < 4; i++)
        #pragma unroll
        for (int j = 0; j < 4; j++)
          acc[i][j] = fmaf(fs[i], vs[j], acc[i][j]);
    }
    if (dhalf == 0 && tid < F_) {
      float s = 0.f;
      #pragma unroll
      for (int cc = 0; cc < ACHUNK; ++cc) s += fk_s[cc][tid];
      sacc += s;
    }
  }

  // ----- epilogue: H_new = H_sum + acc, S_new = S_sum + sacc ------------
  const float* Hs = H_sum + (size_t)pair * F_ * D_;
  float* Hn = H_new + (size_t)pair * F_ * D_;
  #pragma unroll
  for (int i = 0; i < 4; i++) {
    size_t off = (size_t)(f0 + i) * D_ + dhalf * (D_ / 2) + d0;
    float4 hv = *(const float4*)&Hs[off];
    hv.x += acc[i][0]; hv.y += acc[i][1]; hv.z += acc[i][2]; hv.w += acc[i][3];
    *(float4*)&Hn[off] = hv;
  }
  if (dhalf == 0 && tid < F_)
    S_new[(size_t)pair * F_ + tid] = S_sum[(size_t)pair * F_ + tid] + sacc;
}

extern "C" void kernel_launch(void* const* d_in, const int* in_sizes, int n_in,
                              void* d_out, int out_size, void* d_ws, size_t ws_size,
                              hipStream_t stream) {
  const float* heap_score = (const float*)d_in[0];
  const float* K_top  = (const float*)d_in[1];
  const float* V_top  = (const float*)d_in[2];
  const float* FK_top = (const float*)d_in[3];
  const float* H_sum  = (const float*)d_in[4];
  const float* S_sum  = (const float*)d_in[5];
  const float* k_c    = (const float*)d_in[6];
  const float* v_c    = (const float*)d_in[7];
  const float* fk_c   = (const float*)d_in[8];
  const float* score_c = (const float*)d_in[9];

  float* out = (float*)d_out;
  float* heap_new = out;                                        // B*G*H
  float* K_new  = heap_new + (size_t)B_ * G_ * H_;              // B*G*H*D
  float* V_new  = K_new + (size_t)B_ * G_ * H_ * D_;
  float* FK_new = V_new + (size_t)B_ * G_ * H_ * D_;            // B*G*H*F
  float* H_new  = FK_new + (size_t)B_ * G_ * H_ * F_;           // B*H*F*D
  float* S_new  = H_new + (size_t)B_ * H_ * F_ * D_;            // B*H*F

  int* ws_idx = (int*)d_ws;                                     // 655360 B

  sort_kernel<<<B_ * H_, 512, 0, stream>>>(heap_score, score_c, heap_new, ws_idx);

  fused_kernel<<<ABLOCKS + NG, 256, 0, stream>>>(
      (const float4*)K_top, (const float4*)k_c,
      (const float4*)V_top, (const float4*)v_c,
      (const float4*)FK_top, (const float4*)fk_c,
      (float4*)K_new, (float4*)V_new, (float4*)FK_new,
      H_sum, S_sum, H_new, S_new, ws_idx);
}

// Round 11
// 101.084 us; speedup vs baseline: 1.0441x; 1.0181x over previous
//
#include <hip/hip_runtime.h>
#include <stdint.h>

#define B_ 2
#define C_ 512
#define G_ 2048
#define H_ 32
#define D_ 128
#define F_ 64
#define N_ (G_ + C_)      // 2560
#define NPAD 4096

// padded LDS slot for the sort's cross-wave exchanges
#define PIDX(i) ((i) + ((i) >> 4))

// native vector type for __builtin_nontemporal_* (HIP float4 is a class and
// is rejected by the builtin; this alias is layout-identical)
typedef float nt_f4 __attribute__((ext_vector_type(4)));

__device__ __forceinline__ unsigned long long shfl64_xor(unsigned long long x,
                                                         int lanex) {
  unsigned int lo = (unsigned int)x, hi = (unsigned int)(x >> 32);
  lo = __shfl_xor(lo, lanex, 64);
  hi = __shfl_xor(hi, lanex, 64);
  return ((unsigned long long)hi << 32) | (unsigned long long)lo;
}

// ---------------------------------------------------------------------------
// Kernel 1: per-(b,h) stable descending argsort of 2560 scores.
// Bitonic sort of 4096 uint64 keys, 512 threads x 8 register-resident elems.
// key = (~orderable(score) << 32) | index  (unique keys -> exact stable sort).
// Verified bit-exact (rounds 4/7/8/9/10: absmax 0.0).
// ---------------------------------------------------------------------------
__global__ __launch_bounds__(512) void sort_kernel(
    const float* __restrict__ heap_score,   // (B,G,H)
    const float* __restrict__ score_c,      // (B,C,H)
    float* __restrict__ heap_new,           // (B,G,H)
    int* __restrict__ ws_idx)               // (B*H, 2560)
{
  __shared__ unsigned long long keys[NPAD + (NPAD >> 4)];   // 34 KB
  const int blk = blockIdx.x;               // b*H + h
  const int b = blk >> 5, h = blk & 31;
  const int tid = threadIdx.x;

  unsigned long long v[8];
  #pragma unroll
  for (int l = 0; l < 8; ++l) {
    int r = tid * 8 + l;
    unsigned long long key = 0xFFFFFFFFFFFFFFFFull;   // dummy sinks to end
    if (r < N_) {
      float s = (r < G_) ? heap_score[((size_t)b * G_ + r) * H_ + h]
                         : score_c[((size_t)b * C_ + (r - G_)) * H_ + h];
      unsigned int bits = __float_as_uint(s);
      unsigned int ord = (bits & 0x80000000u) ? ~bits : (bits | 0x80000000u);
      key = ((unsigned long long)(~ord) << 32) | (unsigned int)r;
    }
    v[l] = key;
  }

  auto ce = [&](int x, int y, bool desc) {
    unsigned long long a = v[x], c = v[y];
    if ((a > c) != desc) { v[x] = c; v[y] = a; }
  };

  // ---- build sorted runs of 8 (stages k=2,4,8; i = 8*tid + l) ------------
  {
    const bool t1 = (tid & 1) != 0;         // (i & 8)
    ce(0,1,false); ce(2,3,true);  ce(4,5,false); ce(6,7,true);   // k=2
    ce(0,2,false); ce(1,3,false); ce(4,6,true);  ce(5,7,true);   // k=4 j=2
    ce(0,1,false); ce(2,3,false); ce(4,5,true);  ce(6,7,true);   // k=4 j=1
    ce(0,4,t1); ce(1,5,t1); ce(2,6,t1); ce(3,7,t1);              // k=8 j=4
    ce(0,2,t1); ce(1,3,t1); ce(4,6,t1); ce(5,7,t1);              // k=8 j=2
    ce(0,1,t1); ce(2,3,t1); ce(4,5,t1); ce(6,7,t1);              // k=8 j=1
  }

  // ---- stages k=16..4096 --------------------------------------------------
  for (int k = 16; k <= NPAD; k <<= 1) {
    const bool desc = (((unsigned)tid << 3) & (unsigned)k) != 0;  // (8t & k)

    for (int j = k >> 1; j >= 512; j >>= 1) {         // cross-wave: LDS
      __syncthreads();                                 // protect prior reads
      #pragma unroll
      for (int l = 0; l < 8; ++l) keys[PIDX(tid * 8 + l)] = v[l];
      __syncthreads();
      const int pt = tid ^ (j >> 3);
      const bool up = (tid & (j >> 3)) != 0;
      #pragma unroll
      for (int l = 0; l < 8; ++l) {
        unsigned long long o = keys[PIDX(pt * 8 + l)];
        unsigned long long mn = (v[l] < o) ? v[l] : o;
        unsigned long long mx = (v[l] < o) ? o : v[l];
        v[l] = (up != desc) ? mx : mn;
      }
    }

    #pragma unroll
    for (int j = 256; j >= 8; j >>= 1) {              // in-wave: shuffles
      if (j <= (k >> 1)) {
        const int lanex = j >> 3;                     // 1..32
        const bool up = (tid & lanex) != 0;
        #pragma unroll
        for (int l = 0; l < 8; ++l) {
          unsigned long long o = shfl64_xor(v[l], lanex);
          unsigned long long mn = (v[l] < o) ? v[l] : o;
          unsigned long long mx = (v[l] < o) ? o : v[l];
          v[l] = (up != desc) ? mx : mn;
        }
      }
    }

    ce(0,4,desc); ce(1,5,desc); ce(2,6,desc); ce(3,7,desc);      // j=4
    ce(0,2,desc); ce(1,3,desc); ce(4,6,desc); ce(5,7,desc);      // j=2
    ce(0,1,desc); ce(2,3,desc); ce(4,5,desc); ce(6,7,desc);      // j=1
  }

  // ---- outputs straight from registers -----------------------------------
  if (tid < N_ / 8) {                                  // tid < 320
    int4 lo4 = { (int)(unsigned)v[0], (int)(unsigned)v[1],
                 (int)(unsigned)v[2], (int)(unsigned)v[3] };
    int4 hi4 = { (int)(unsigned)v[4], (int)(unsigned)v[5],
                 (int)(unsigned)v[6], (int)(unsigned)v[7] };
    int4* p = (int4*)(ws_idx + (size_t)blk * N_);
    p[2 * tid] = lo4;
    p[2 * tid + 1] = hi4;
  }
  if (tid < G_ / 8) {                                  // tid < 256
    #pragma unroll
    for (int l = 0; l < 8; ++l) {
      int r = tid * 8 + l;
      unsigned int ord = ~(unsigned int)(v[l] >> 32);
      unsigned int bits = (ord & 0x80000000u) ? (ord & 0x7FFFFFFFu) : ~ord;
      heap_new[((size_t)b * G_ + r) * H_ + h] = __uint_as_float(bits);
    }
  }
}

// ---------------------------------------------------------------------------
// Kernel 2: fused gather + accumulation (best-verified R8 configuration).
//  blocks [0, ABLOCKS): accum — 2 blocks per (b,h) (one per d-half), direct
//    H_new = H_sum + sum over 512 bottom rows (bit-exact vs np since R7).
//  blocks [ABLOCKS, +NG): gather — ILP-8: 8 independent idx->data chains per
//    thread; all idx loads, then 8 NT loads (read-once, keep L2 clean), then
//    8 plain-path stores.
// ---------------------------------------------------------------------------
#define NK4 ((long long)B_ * G_ * H_ * (D_ / 4))       // 4194304
#define NTOT4 ((long long)B_ * G_ * H_ * (2 * (D_ / 4) + (F_ / 4)))  // 10485760
#define EIGHTH (NTOT4 / 8)                             // 1310720 (mult of 256)
#define NG ((int)(EIGHTH / 256))                       // 5120 gather blocks
#define ABLOCKS (2 * B_ * H_)                          // 128 accum blocks
#define ACHUNK 16
#define AITER (C_ / ACHUNK)                            // 32

__device__ __forceinline__ void gather_one(
    long long gid,
    const float4* __restrict__ K_top,  const float4* __restrict__ k_c,
    const float4* __restrict__ V_top,  const float4* __restrict__ v_c,
    const float4* __restrict__ FK_top, const float4* __restrict__ fk_c,
    float4* __restrict__ K_new, float4* __restrict__ V_new,
    float4* __restrict__ FK_new,
    const int* __restrict__ ws_idx,
    const nt_f4** src, float4** dst)
{
  const float4 *top, *cc;
  float4* d;
  int lg;
  long long g2;
  if (gid < NK4)          { top = K_top;  cc = k_c;  d = K_new;  lg = 5; g2 = gid; }
  else if (gid < 2 * NK4) { top = V_top;  cc = v_c;  d = V_new;  lg = 5; g2 = gid - NK4; }
  else                    { top = FK_top; cc = fk_c; d = FK_new; lg = 4; g2 = gid - 2 * NK4; }

  int row = (int)(g2 >> lg);                // [0, B*G*H)
  int lane = (int)(g2 & ((1 << lg) - 1));
  int b = row >> 16;                        // G*H = 65536
  int g = (row >> 5) & (G_ - 1);
  int h = row & 31;
  int idx = ws_idx[((b << 5) | h) * N_ + g];
  const float4* s;
  if (idx < G_) s = top + (((size_t)(b * G_ + idx) * H_ + h) << lg) + lane;
  else          s = cc  + (((size_t)(b * C_ + (idx - G_)) * H_ + h) << lg) + lane;
  *src = (const nt_f4*)s;
  *dst = d + g2;
}

__global__ __launch_bounds__(256) void fused_kernel(
    const float4* __restrict__ K_top,  const float4* __restrict__ k_c,
    const float4* __restrict__ V_top,  const float4* __restrict__ v_c,
    const float4* __restrict__ FK_top, const float4* __restrict__ fk_c,
    float4* __restrict__ K_new, float4* __restrict__ V_new,
    float4* __restrict__ FK_new,
    const float* __restrict__ H_sum, const float* __restrict__ S_sum,
    float* __restrict__ H_new, float* __restrict__ S_new,
    const int* __restrict__ ws_idx)
{
  __shared__ float fk_s[ACHUNK][F_];        // 4 KB
  __shared__ float v_s[ACHUNK][D_ / 2];     // 4 KB
  __shared__ int idx_all[C_];               // 2 KB

  const int tid = threadIdx.x;

  if (blockIdx.x >= ABLOCKS) {
    // ----- gather: ILP-8, NT loads + plain stores -----------------------
    long long gid = (long long)(blockIdx.x - ABLOCKS) * 256 + tid;

    const nt_f4* s[8];
    float4* d[8];
    #pragma unroll
    for (int k = 0; k < 8; ++k)
      gather_one(gid + (long long)k * EIGHTH, K_top, k_c, V_top, v_c,
                 FK_top, fk_c, K_new, V_new, FK_new, ws_idx, &s[k], &d[k]);
    nt_f4 val[8];
    #pragma unroll
    for (int k = 0; k < 8; ++k) val[k] = __builtin_nontemporal_load(s[k]);
    #pragma unroll
    for (int k = 0; k < 8; ++k) *(nt_f4*)d[k] = val[k];
    return;
  }

  // ----- accum: one block per (b,h) x d-half ----------------------------
  const int pair = blockIdx.x >> 1;         // 0..63
  const int dhalf = blockIdx.x & 1;
  const int b = pair >> 5, h = pair & 31;

  for (int i = tid; i < C_; i += 256)
    idx_all[i] = ws_idx[(size_t)pair * N_ + G_ + i];

  const int f0 = (tid >> 4) * 4;            // 0..60 (global f)
  const int d0 = (tid & 15) * 4;            // 0..60 (within half)
  float acc[4][4];
  #pragma unroll
  for (int i = 0; i < 4; i++)
    #pragma unroll
    for (int j = 0; j < 4; j++) acc[i][j] = 0.f;
  float sacc = 0.f;

  const int rr = tid >> 4, lane = tid & 15; // staging role: row, f4-slot

  for (int it = 0; it < AITER; ++it) {
    __syncthreads();                        // idx ready / prev compute done
    int idx = idx_all[it * ACHUNK + rr];
    {                                       // V half: 256 f4, 1 per thread
      const float4* src = (idx < G_)
          ? V_top + (((size_t)(b * G_ + idx) * H_ + h) << 5)
          : v_c  + (((size_t)(b * C_ + (idx - G_)) * H_ + h) << 5);
      ((float4*)v_s)[tid] = src[dhalf * 16 + lane];
    }
    {                                       // FK: 256 f4, 1 per thread
      const float4* src = (idx < G_)
          ? FK_top + (((size_t)(b * G_ + idx) * H_ + h) << 4)
          : fk_c  + (((size_t)(b * C_ + (idx - G_)) * H_ + h) << 4);
      ((float4*)fk_s)[tid] = src[lane];
    }
    __syncthreads();

    #pragma unroll 4
    for (int cc = 0; cc < ACHUNK; ++cc) {
      float4 fk4 = *(const float4*)&fk_s[cc][f0];
      float4 vv = *(const float4*)&v_s[cc][d0];
      float fs[4] = {fk4.x, fk4.y, fk4.z, fk4.w};
      float vs[4] = {vv.x, vv.y, vv.z, vv.w};
      #pragma unroll
      for (int i = 0; i < 4; i++)
        #pragma unroll
        for (int j = 0; j < 4; j++)
          acc[i][j] = fmaf(fs[i], vs[j], acc[i][j]);
    }
    if (dhalf == 0 && tid < F_) {
      float s = 0.f;
      #pragma unroll
      for (int cc = 0; cc < ACHUNK; ++cc) s += fk_s[cc][tid];
      sacc += s;
    }
  }

  // ----- epilogue: H_new = H_sum + acc, S_new = S_sum + sacc ------------
  const float* Hs = H_sum + (size_t)pair * F_ * D_;
  float* Hn = H_new + (size_t)pair * F_ * D_;
  #pragma unroll
  for (int i = 0; i < 4; i++) {
    size_t off = (size_t)(f0 + i) * D_ + dhalf * (D_ / 2) + d0;
    float4 hv = *(const float4*)&Hs[off];
    hv.x += acc[i][0]; hv.y += acc[i][1]; hv.z += acc[i][2]; hv.w += acc[i][3];
    *(float4*)&Hn[off] = hv;
  }
  if (dhalf == 0 && tid < F_)
    S_new[(size_t)pair * F_ + tid] = S_sum[(size_t)pair * F_ + tid] + sacc;
}

extern "C" void kernel_launch(void* const* d_in, const int* in_sizes, int n_in,
                              void* d_out, int out_size, void* d_ws, size_t ws_size,
                              hipStream_t stream) {
  const float* heap_score = (const float*)d_in[0];
  const float* K_top  = (const float*)d_in[1];
  const float* V_top  = (const float*)d_in[2];
  const float* FK_top = (const float*)d_in[3];
  const float* H_sum  = (const float*)d_in[4];
  const float* S_sum  = (const float*)d_in[5];
  const float* k_c    = (const float*)d_in[6];
  const float* v_c    = (const float*)d_in[7];
  const float* fk_c   = (const float*)d_in[8];
  const float* score_c = (const float*)d_in[9];

  float* out = (float*)d_out;
  float* heap_new = out;                                        // B*G*H
  float* K_new  = heap_new + (size_t)B_ * G_ * H_;              // B*G*H*D
  float* V_new  = K_new + (size_t)B_ * G_ * H_ * D_;
  float* FK_new = V_new + (size_t)B_ * G_ * H_ * D_;            // B*G*H*F
  float* H_new  = FK_new + (size_t)B_ * G_ * H_ * F_;           // B*H*F*D
  float* S_new  = H_new + (size_t)B_ * H_ * F_ * D_;            // B*H*F

  int* ws_idx = (int*)d_ws;                                     // 655360 B

  sort_kernel<<<B_ * H_, 512, 0, stream>>>(heap_score, score_c, heap_new, ws_idx);

  fused_kernel<<<ABLOCKS + NG, 256, 0, stream>>>(
      (const float4*)K_top, (const float4*)k_c,
      (const float4*)V_top, (const float4*)v_c,
      (const float4*)FK_top, (const float4*)fk_c,
      (float4*)K_new, (float4*)V_new, (float4*)FK_new,
      H_sum, S_sum, H_new, S_new, ws_idx);
}